// Round 1
// baseline (752.569 us; speedup 1.0000x reference)
//
#include <hip/hip_runtime.h>
#include <hip/hip_bf16.h>
#include <math.h>

// Problem constants (match reference)
constexpr int N_EMBD = 1024;
constexpr int T_SEQ  = 128;   // BLOCK_SIZE
constexpr int HS     = 128;   // HEAD_SIZE
constexpr int BATCH  = 256;
constexpr int ROWS   = BATCH * T_SEQ;   // 32768

// ---------------- Kernel 1: QKV projection + RoPE ----------------
// Block: 256 threads. Each block handles RPB=32 rows of x.
//   half = tid>>7 selects rows [half*16, half*16+16); d = tid&127 is the output column.
// x tile staged in LDS in KC=256 chunks; per k-index each thread does 3 FMAs/row
// (q,k,v) against one W element each -> 48 FMA per LDS broadcast quad.
constexpr int RPB = 32;
constexpr int KC  = 256;

__global__ __launch_bounds__(256) void qkv_rope_kernel(
    const float* __restrict__ x,
    const float* __restrict__ Wq,
    const float* __restrict__ Wk,
    const float* __restrict__ Wv,
    float* __restrict__ qo,
    float* __restrict__ ko,
    float* __restrict__ vo)
{
    __shared__ float xs[RPB][KC];

    const int tid  = threadIdx.x;
    const int half = tid >> 7;      // 0 or 1
    const int d    = tid & 127;
    const int row0 = blockIdx.x * RPB;

    float acc_q[16], acc_k[16], acc_v[16];
#pragma unroll
    for (int r = 0; r < 16; ++r) { acc_q[r] = 0.f; acc_k[r] = 0.f; acc_v[r] = 0.f; }

    for (int kc = 0; kc < N_EMBD; kc += KC) {
        __syncthreads();
        // cooperative load: 32x256 floats = 2048 float4, 8 per thread, coalesced
#pragma unroll
        for (int l = 0; l < 8; ++l) {
            int idx = tid + l * 256;          // float4 index 0..2047
            int r   = idx >> 6;               // 64 float4 per row
            int c   = (idx & 63) << 2;
            *(float4*)&xs[r][c] =
                *(const float4*)&x[(size_t)(row0 + r) * N_EMBD + kc + c];
        }
        __syncthreads();

        for (int i = 0; i < KC; i += 4) {
            float4 xv[16];
#pragma unroll
            for (int r = 0; r < 16; ++r)
                xv[r] = *(const float4*)&xs[half * 16 + r][i];
#pragma unroll
            for (int u = 0; u < 4; ++u) {
                size_t wrow = (size_t)(kc + i + u) * HS + d;
                float wq = Wq[wrow];
                float wk = Wk[wrow];
                float wv = Wv[wrow];
#pragma unroll
                for (int r = 0; r < 16; ++r) {
                    float xvv = (&xv[r].x)[u];
                    acc_q[r] = fmaf(xvv, wq, acc_q[r]);
                    acc_k[r] = fmaf(xvv, wk, acc_k[r]);
                    acc_v[r] = fmaf(xvv, wv, acc_v[r]);
                }
            }
        }
    }

    // RoPE epilogue. pair index i = d>>1; inv_freq = exp(-(d&~1)*ln(theta)/hs)
    const float freq = expf(-(float)(d & ~1) * 0.07195578430905272f); // ln(10000)/128
#pragma unroll
    for (int r = 0; r < 16; ++r) {
        int row = row0 + half * 16 + r;
        int t   = row & (T_SEQ - 1);
        float sn, cs;
        sincosf((float)t * freq, &sn, &cs);

        float pq = __shfl_xor(acc_q[r], 1);
        float pk = __shfl_xor(acc_k[r], 1);
        float rq, rk;
        if ((d & 1) == 0) {   // even: tr*cos - ti*sin  (own = tr, partner = ti)
            rq = acc_q[r] * cs - pq * sn;
            rk = acc_k[r] * cs - pk * sn;
        } else {              // odd:  tr*sin + ti*cos  (partner = tr, own = ti)
            rq = pq * sn + acc_q[r] * cs;
            rk = pk * sn + acc_k[r] * cs;
        }
        size_t o = (size_t)row * HS + d;
        qo[o] = rq;
        ko[o] = rk;
        vo[o] = acc_v[r];
    }
}

// ---------------- Kernel 2: causal attention ----------------
// One block (128 threads) per output row (b,t).
// Phase 1: thread s computes score_s = q.k_s (s<=t), else -inf.
// Phase 2: two-wave softmax reduction (max, sum).
// Phase 3: thread d accumulates sum_s p_s * v[s][d] (coalesced v reads).
__device__ __forceinline__ float wave_max(float v) {
#pragma unroll
    for (int o = 32; o > 0; o >>= 1) v = fmaxf(v, __shfl_xor(v, o));
    return v;
}
__device__ __forceinline__ float wave_sum(float v) {
#pragma unroll
    for (int o = 32; o > 0; o >>= 1) v += __shfl_xor(v, o);
    return v;
}

__global__ __launch_bounds__(128) void attn_kernel(
    const float* __restrict__ q,
    const float* __restrict__ k,
    const float* __restrict__ v,
    float* __restrict__ out)
{
    const int tid = threadIdx.x;
    const int b   = blockIdx.x >> 7;
    const int t   = blockIdx.x & 127;

    __shared__ float q_lds[HS];
    __shared__ float p_lds[T_SEQ];
    __shared__ float red[4];

    const size_t rowoff = (size_t)blockIdx.x * HS;
    q_lds[tid] = q[rowoff + tid];
    __syncthreads();

    float score = -INFINITY;
    if (tid <= t) {
        const float* krow = k + ((size_t)(b * T_SEQ + tid) * HS);
        float acc = 0.f;
#pragma unroll
        for (int d0 = 0; d0 < HS; d0 += 4) {
            float4 kv = *(const float4*)(krow + d0);
            acc = fmaf(q_lds[d0],     kv.x, acc);
            acc = fmaf(q_lds[d0 + 1], kv.y, acc);
            acc = fmaf(q_lds[d0 + 2], kv.z, acc);
            acc = fmaf(q_lds[d0 + 3], kv.w, acc);
        }
        score = acc * 0.08838834764831845f;  // 1/sqrt(128)
    }

    // max over 128 threads
    float m = wave_max(score);
    if ((tid & 63) == 0) red[tid >> 6] = m;
    __syncthreads();
    m = fmaxf(red[0], red[1]);

    float p = expf(score - m);   // -inf -> 0
    float s = wave_sum(p);
    __syncthreads();             // protect red reuse
    if ((tid & 63) == 0) red[2 + (tid >> 6)] = s;
    p_lds[tid] = p;
    __syncthreads();
    const float inv_sum = 1.0f / (red[2] + red[3]);

    float o = 0.f;
    const float* vb = v + (size_t)b * T_SEQ * HS;
    for (int si = 0; si <= t; ++si)
        o = fmaf(p_lds[si], vb[(size_t)si * HS + tid], o);

    out[rowoff + tid] = o * inv_sum;
}

// ---------------- launch ----------------
extern "C" void kernel_launch(void* const* d_in, const int* in_sizes, int n_in,
                              void* d_out, int out_size, void* d_ws, size_t ws_size,
                              hipStream_t stream) {
    const float* x  = (const float*)d_in[0];
    const float* Wq = (const float*)d_in[1];
    const float* Wk = (const float*)d_in[2];
    const float* Wv = (const float*)d_in[3];
    float* out = (float*)d_out;

    // workspace: q, k, v each ROWS*HS fp32 (16 MB each)
    float* qw = (float*)d_ws;
    float* kw = qw + (size_t)ROWS * HS;
    float* vw = kw + (size_t)ROWS * HS;

    qkv_rope_kernel<<<ROWS / RPB, 256, 0, stream>>>(x, Wq, Wk, Wv, qw, kw, vw);
    attn_kernel<<<ROWS, 128, 0, stream>>>(qw, kw, vw, out);
}

// Round 2
// 264.470 us; speedup vs baseline: 2.8456x; 2.8456x over previous
//
#include <hip/hip_runtime.h>
#include <math.h>

typedef __bf16 bf16x8 __attribute__((ext_vector_type(8)));
typedef float  f32x4  __attribute__((ext_vector_type(4)));
typedef unsigned short us4 __attribute__((ext_vector_type(4)));

constexpr int N_EMBD = 1024;
constexpr int T_SEQ  = 128;
constexpr int HS     = 128;
constexpr int BATCH  = 256;
constexpr int ROWS   = BATCH * T_SEQ;   // 32768

__device__ __forceinline__ void async16(const void* g, void* l) {
    __builtin_amdgcn_global_load_lds(
        (const __attribute__((address_space(1))) unsigned int*)g,
        (__attribute__((address_space(3))) unsigned int*)l, 16, 0, 0);
}
__device__ __forceinline__ unsigned short bfbits(float f) {
    return __builtin_bit_cast(unsigned short, (__bf16)f);
}
__device__ __forceinline__ f32x4 zero4() {
    f32x4 z = {0.f, 0.f, 0.f, 0.f};
    return z;
}

// ---------------- Kernel 0: W cast + transpose ----------------
// Wt[nt*128 + n][k] = W_nt[k][n] as bf16.  48 blocks = 3 nt x 16 k-chunks.
__global__ __launch_bounds__(256) void wcast(
    const float* __restrict__ Wq, const float* __restrict__ Wk,
    const float* __restrict__ Wv, unsigned short* __restrict__ Wt)
{
    __shared__ unsigned short tile[64][130];   // +2 pad: conflict-free transpose read
    const int bid = blockIdx.x;
    const int nt  = bid >> 4;
    const int k0  = (bid & 15) << 6;
    const float* src = (nt == 0) ? Wq : ((nt == 1) ? Wk : Wv);
    const int tid = threadIdx.x;
#pragma unroll
    for (int j = 0; j < 32; ++j) {
        int idx = tid + j * 256;          // 64x128 elements
        int k = idx >> 7, n = idx & 127;
        tile[k][n] = bfbits(src[(size_t)(k0 + k) * HS + n]);
    }
    __syncthreads();
#pragma unroll
    for (int j = 0; j < 32; ++j) {
        int idx = tid + j * 256;
        int n = idx >> 6, kk = idx & 63;
        Wt[(size_t)(nt * 128 + n) * N_EMBD + k0 + kk] = tile[kk][n];
    }
}

// ---------------- Kernel 1: QKV GEMM (MFMA) + RoPE ----------------
// 768 blocks: nt = bid>>8 (0=q,1=k,2=v), mt = bid&255 (128-row tile = one batch).
// 4 waves, each owns a 64x64 quadrant: acc[4][4] 16x16 tiles.
// A (x, fp32) staged via global_load_lds into XOR-swizzled LDS, cvt->bf16 at frag
// build. B (Wt, bf16) staged likewise. Swizzle keeps global_load_lds contiguity
// while capping ds_read_b128 conflicts at 2-way (free).
__global__ __launch_bounds__(256) void qkv_gemm(
    const float* __restrict__ x,
    const unsigned short* __restrict__ Wt,
    unsigned short* __restrict__ qb,
    unsigned short* __restrict__ kb,
    unsigned short* __restrict__ vt)
{
    __shared__ char lds[49152];   // A fp32 32768 B | B bf16 16384 B
    const int tid = threadIdx.x;
    const int w  = tid >> 6;
    const int l  = tid & 63;
    const int cl = l & 15;
    const int quad = l >> 4;
    const int nt  = blockIdx.x >> 8;
    const int mt  = blockIdx.x & 255;
    const int row0 = mt << 7;
    const int wm0 = (w & 1) << 6;
    const int wn0 = (w >> 1) << 6;

    f32x4 acc[4][4];
#pragma unroll
    for (int a = 0; a < 4; ++a)
#pragma unroll
        for (int b = 0; b < 4; ++b) acc[a][b] = zero4();

    for (int kc = 0; kc < N_EMBD; kc += 64) {
        __syncthreads();
        // stage A: 128 rows x 64 fp32 = 32 KB = 32 wave-instrs; LDS slot(m,c) holds
        // global chunk (m, c ^ (m&15)), chunk = 16 B = 4 floats.
#pragma unroll
        for (int jj = 0; jj < 8; ++jj) {
            int j = w * 8 + jj;
            int m = j * 4 + (l >> 4);
            int csrc = (l & 15) ^ (m & 15);
            async16(x + (size_t)(row0 + m) * N_EMBD + kc + csrc * 4, lds + j * 1024);
        }
        // stage B: 128 n x 64 bf16 = 16 KB; slot(n,c) holds (n, c ^ (n&7)), chunk = 8 bf16.
#pragma unroll
        for (int jj = 0; jj < 4; ++jj) {
            int j = w * 4 + jj;
            int n = j * 8 + (l >> 3);
            int csrc = (l & 7) ^ (l >> 3);
            async16(Wt + (size_t)(nt * 128 + n) * N_EMBD + kc + csrc * 8,
                    lds + 32768 + j * 1024);
        }
        __syncthreads();

#pragma unroll
        for (int ks = 0; ks < 2; ++ks) {
            const int kq = ks * 4 + quad;       // 16B-chunk index along K (bf16 units)
            bf16x8 af[4], bf[4];
#pragma unroll
            for (int rt = 0; rt < 4; ++rt) {
                int m = wm0 + rt * 16 + cl;     // m&15 == cl
                int c0 = kq * 2;
                f32x4 a0 = *(const f32x4*)(lds + ((m * 16 + (c0 ^ cl)) << 4));
                f32x4 a1 = *(const f32x4*)(lds + ((m * 16 + ((c0 + 1) ^ cl)) << 4));
                bf16x8 t;
                t[0] = (__bf16)a0[0]; t[1] = (__bf16)a0[1];
                t[2] = (__bf16)a0[2]; t[3] = (__bf16)a0[3];
                t[4] = (__bf16)a1[0]; t[5] = (__bf16)a1[1];
                t[6] = (__bf16)a1[2]; t[7] = (__bf16)a1[3];
                af[rt] = t;
            }
#pragma unroll
            for (int ct = 0; ct < 4; ++ct) {
                int n = wn0 + ct * 16 + cl;     // n&7 == l&7
                bf[ct] = *(const bf16x8*)(lds + 32768 + ((n * 8 + (kq ^ (l & 7))) << 4));
            }
#pragma unroll
            for (int rt = 0; rt < 4; ++rt)
#pragma unroll
                for (int ct = 0; ct < 4; ++ct)
                    acc[rt][ct] = __builtin_amdgcn_mfma_f32_16x16x32_bf16(
                        af[rt], bf[ct], acc[rt][ct], 0, 0, 0);
        }
    }

    // Epilogue. C layout: col = cl (within tile), row = quad*4 + i.
    if (nt < 2) {
        unsigned short* dst = (nt == 0) ? qb : kb;
        const float LNT = 0.07195578430905272f;  // ln(10000)/128
#pragma unroll
        for (int ct = 0; ct < 4; ++ct) {
            int c = wn0 + ct * 16 + cl;
            float freq = __expf(-(float)(c & ~1) * LNT);
#pragma unroll
            for (int rt = 0; rt < 4; ++rt) {
#pragma unroll
                for (int i = 0; i < 4; ++i) {
                    int t = wm0 + rt * 16 + quad * 4 + i;
                    float v = acc[rt][ct][i];
                    float p = __shfl_xor(v, 1);
                    float sn, cs;
                    __sincosf((float)t * freq, &sn, &cs);
                    float r = ((c & 1) == 0) ? (v * cs - p * sn) : (p * sn + v * cs);
                    dst[(size_t)(row0 + t) * HS + c] = bfbits(r);
                }
            }
        }
    } else {
        // v: write transposed vt[b][d][s], 4 consecutive s per (rt,ct) -> 8 B store
#pragma unroll
        for (int ct = 0; ct < 4; ++ct) {
            int d = wn0 + ct * 16 + cl;
#pragma unroll
            for (int rt = 0; rt < 4; ++rt) {
                int s0 = wm0 + rt * 16 + quad * 4;
                us4 u;
                u.x = bfbits(acc[rt][ct][0]);
                u.y = bfbits(acc[rt][ct][1]);
                u.z = bfbits(acc[rt][ct][2]);
                u.w = bfbits(acc[rt][ct][3]);
                *(us4*)(vt + (size_t)mt * 16384 + d * 128 + s0) = u;
            }
        }
    }
}

// ---------------- Kernel 2: causal attention (MFMA, flash-lite) ----------------
// 1024 blocks x 64 threads (1 wave). Block = (b = bid>>2, rg = bid&3): Q rows
// [rg*32, rg*32+32). Frags loaded from global (L1/L2-hot, 32 KB/array/batch).
// Causal skip: score tiles ct < 2rg+2 only; PV k-chunks ks <= rg only.
// P: C-layout -> bf16 LDS [t][s] (stride 272 B, 2-way conflicts max) -> A-layout.
__global__ __launch_bounds__(64) void attn(
    const unsigned short* __restrict__ qb,
    const unsigned short* __restrict__ kb,
    const unsigned short* __restrict__ vt,
    float* __restrict__ out)
{
    __shared__ char plds[32 * 272];
    const int l = threadIdx.x;
    const int cl = l & 15;
    const int quad = l >> 4;
    const int b  = blockIdx.x >> 2;
    const int rg = blockIdx.x & 3;
    const int nct = rg * 2 + 2;

    const unsigned short* qB = qb + (size_t)b * 16384;
    const unsigned short* kB = kb + (size_t)b * 16384;
    const unsigned short* vB = vt + (size_t)b * 16384;

    f32x4 s[2][8];
#pragma unroll
    for (int rt = 0; rt < 2; ++rt)
#pragma unroll
        for (int ct = 0; ct < 8; ++ct) s[rt][ct] = zero4();

    // S = Q K^T   (K dim = d = 128 -> 4 k-steps)
#pragma unroll 1
    for (int ks = 0; ks < 4; ++ks) {
        int kq = ks * 4 + quad;
        bf16x8 a0 = *(const bf16x8*)(qB + (size_t)(rg * 32 + cl) * HS + kq * 8);
        bf16x8 a1 = *(const bf16x8*)(qB + (size_t)(rg * 32 + 16 + cl) * HS + kq * 8);
#pragma unroll
        for (int ct = 0; ct < 8; ++ct) {
            if (ct < nct) {
                bf16x8 bb = *(const bf16x8*)(kB + (size_t)(ct * 16 + cl) * HS + kq * 8);
                s[0][ct] = __builtin_amdgcn_mfma_f32_16x16x32_bf16(a0, bb, s[0][ct], 0, 0, 0);
                s[1][ct] = __builtin_amdgcn_mfma_f32_16x16x32_bf16(a1, bb, s[1][ct], 0, 0, 0);
            }
        }
    }

    // softmax (rows live across the 16 lanes of each quad + 8 ct regs)
    const float scale = 0.08838834764831845f;   // 1/sqrt(128)
#pragma unroll
    for (int rt = 0; rt < 2; ++rt) {
#pragma unroll
        for (int i = 0; i < 4; ++i) {
            int t = rg * 32 + rt * 16 + quad * 4 + i;
            float mx = -3.0e38f;
#pragma unroll
            for (int ct = 0; ct < 8; ++ct) if (ct < nct) {
                int col = ct * 16 + cl;
                float v = s[rt][ct][i] * scale;
                v = (col <= t) ? v : -INFINITY;
                s[rt][ct][i] = v;
                mx = fmaxf(mx, v);
            }
            mx = fmaxf(mx, __shfl_xor(mx, 1));
            mx = fmaxf(mx, __shfl_xor(mx, 2));
            mx = fmaxf(mx, __shfl_xor(mx, 4));
            mx = fmaxf(mx, __shfl_xor(mx, 8));
            float sum = 0.f;
#pragma unroll
            for (int ct = 0; ct < 8; ++ct) if (ct < nct) {
                float p = __expf(s[rt][ct][i] - mx);
                s[rt][ct][i] = p;
                sum += p;
            }
            sum += __shfl_xor(sum, 1);
            sum += __shfl_xor(sum, 2);
            sum += __shfl_xor(sum, 4);
            sum += __shfl_xor(sum, 8);
            float inv = 1.0f / sum;
            int rl = rt * 16 + quad * 4 + i;
#pragma unroll
            for (int ct = 0; ct < 8; ++ct) if (ct < nct) {
                *(unsigned short*)(plds + rl * 272 + (ct * 16 + cl) * 2) =
                    bfbits(s[rt][ct][i] * inv);
            }
        }
    }
    // same-wave ds_write -> ds_read: compiler inserts lgkmcnt wait; no barrier needed.

    // O = P V   (K dim = s, only ks <= rg chunks are nonzero)
    f32x4 o[2][8];
#pragma unroll
    for (int rt = 0; rt < 2; ++rt)
#pragma unroll
        for (int ct = 0; ct < 8; ++ct) o[rt][ct] = zero4();

    const int nks = rg + 1;
    for (int ks = 0; ks < nks; ++ks) {
        int kq = ks * 4 + quad;
        bf16x8 a0 = *(const bf16x8*)(plds + cl * 272 + kq * 16);
        bf16x8 a1 = *(const bf16x8*)(plds + (16 + cl) * 272 + kq * 16);
#pragma unroll
        for (int ct = 0; ct < 8; ++ct) {
            bf16x8 bb = *(const bf16x8*)(vB + (size_t)(ct * 16 + cl) * 128 + kq * 8);
            o[0][ct] = __builtin_amdgcn_mfma_f32_16x16x32_bf16(a0, bb, o[0][ct], 0, 0, 0);
            o[1][ct] = __builtin_amdgcn_mfma_f32_16x16x32_bf16(a1, bb, o[1][ct], 0, 0, 0);
        }
    }

#pragma unroll
    for (int rt = 0; rt < 2; ++rt)
#pragma unroll
        for (int ct = 0; ct < 8; ++ct)
#pragma unroll
            for (int i = 0; i < 4; ++i) {
                int t = rg * 32 + rt * 16 + quad * 4 + i;
                out[(size_t)b * 16384 + (size_t)t * HS + ct * 16 + cl] = o[rt][ct][i];
            }
}

// ---------------- launch ----------------
extern "C" void kernel_launch(void* const* d_in, const int* in_sizes, int n_in,
                              void* d_out, int out_size, void* d_ws, size_t ws_size,
                              hipStream_t stream) {
    const float* x  = (const float*)d_in[0];
    const float* Wq = (const float*)d_in[1];
    const float* Wk = (const float*)d_in[2];
    const float* Wv = (const float*)d_in[3];
    float* out = (float*)d_out;

    // ws: qb 8MB | kb 8MB | vt 8MB | Wt 768KB   (total ~24.8 MB)
    unsigned short* qb = (unsigned short*)d_ws;
    unsigned short* kb = qb + (size_t)ROWS * HS;
    unsigned short* vt = kb + (size_t)ROWS * HS;
    unsigned short* Wt = vt + (size_t)ROWS * HS;

    wcast<<<48, 256, 0, stream>>>(Wq, Wk, Wv, Wt);
    qkv_gemm<<<768, 256, 0, stream>>>(x, Wt, qb, kb, vt);
    attn<<<1024, 64, 0, stream>>>(qb, kb, vt, out);
}

// Round 3
// 250.415 us; speedup vs baseline: 3.0053x; 1.0561x over previous
//
#include <hip/hip_runtime.h>
#include <math.h>

typedef __bf16 bf16x8 __attribute__((ext_vector_type(8)));
typedef float  f32x4  __attribute__((ext_vector_type(4)));
typedef unsigned short us4 __attribute__((ext_vector_type(4)));

constexpr int N_EMBD = 1024;
constexpr int T_SEQ  = 128;
constexpr int HS     = 128;
constexpr int BATCH  = 256;
constexpr int ROWS   = BATCH * T_SEQ;   // 32768

__device__ __forceinline__ void async16(const void* g, void* l) {
    __builtin_amdgcn_global_load_lds(
        (const __attribute__((address_space(1))) unsigned int*)g,
        (__attribute__((address_space(3))) unsigned int*)l, 16, 0, 0);
}
__device__ __forceinline__ unsigned short bfbits(float f) {
    return __builtin_bit_cast(unsigned short, (__bf16)f);
}
__device__ __forceinline__ f32x4 zero4() {
    f32x4 z = {0.f, 0.f, 0.f, 0.f};
    return z;
}

// ---------------- Kernel 0: W cast + transpose ----------------
// Wt[nt*128 + n][k] = W_nt[k][n] as bf16.  48 blocks = 3 nt x 16 k-chunks.
__global__ __launch_bounds__(256) void wcast(
    const float* __restrict__ Wq, const float* __restrict__ Wk,
    const float* __restrict__ Wv, unsigned short* __restrict__ Wt)
{
    __shared__ unsigned short tile[64][130];
    const int bid = blockIdx.x;
    const int nt  = bid >> 4;
    const int k0  = (bid & 15) << 6;
    const float* src = (nt == 0) ? Wq : ((nt == 1) ? Wk : Wv);
    const int tid = threadIdx.x;
#pragma unroll
    for (int j = 0; j < 32; ++j) {
        int idx = tid + j * 256;
        int k = idx >> 7, n = idx & 127;
        tile[k][n] = bfbits(src[(size_t)(k0 + k) * HS + n]);
    }
    __syncthreads();
#pragma unroll
    for (int j = 0; j < 32; ++j) {
        int idx = tid + j * 256;
        int n = idx >> 6, kk = idx & 63;
        Wt[(size_t)(nt * 128 + n) * N_EMBD + k0 + kk] = tile[kk][n];
    }
}

// ---------------- Kernel 1: fused QKV GEMM (MFMA) + RoPE ----------------
// 512 blocks x 512 threads (8 waves). Block = 64-row M-tile x all 384 N cols
// (q|k|v merged -> x read ONCE). Wave tile: rows (w&1)*32 + [0,32), cols
// (w>>2... ) -> wm0=(w&1)*32, wn0=(w>>1)*96: acc[2][6] 16x16 tiles.
// A (x fp32) + B (Wt bf16) staged via global_load_lds, XOR-swizzled LDS
// (wave-contiguity preserved, <=2-way conflicts). A cvt->bf16 at frag build.
__global__ __launch_bounds__(512, 4) void qkv_gemm(
    const float* __restrict__ x,
    const unsigned short* __restrict__ Wt,
    unsigned short* __restrict__ qb,
    unsigned short* __restrict__ kb,
    unsigned short* __restrict__ vt)
{
    __shared__ char lds[65536];   // A fp32 16384 B | B bf16 49152 B
    const int tid = threadIdx.x;
    const int w  = tid >> 6;
    const int l  = tid & 63;
    const int cl = l & 15;
    const int quad = l >> 4;
    const int mt  = blockIdx.x;
    const int row0 = mt << 6;
    const int wm0 = (w & 1) << 5;
    const int wn0 = (w >> 1) * 96;

    f32x4 acc[2][6];
#pragma unroll
    for (int a = 0; a < 2; ++a)
#pragma unroll
        for (int b = 0; b < 6; ++b) acc[a][b] = zero4();

    for (int kc = 0; kc < N_EMBD; kc += 64) {
        __syncthreads();
        // A: 64 rows x 16 chunks(16B). slot(m,sc) holds global chunk (m, sc^(m&15))
#pragma unroll
        for (int jj = 0; jj < 2; ++jj) {
            int j = w * 2 + jj;
            int m = j * 4 + (l >> 4);
            int csrc = (l & 15) ^ (m & 15);
            async16(x + (size_t)(row0 + m) * N_EMBD + kc + csrc * 4, lds + j * 1024);
        }
        // B: 384 n x 8 chunks(16B = 8 bf16). slot(n,sc) holds (n, sc^(n&7))
#pragma unroll
        for (int jj = 0; jj < 6; ++jj) {
            int j = w * 6 + jj;
            int n = j * 8 + (l >> 3);
            int csrc = (l & 7) ^ (l >> 3);
            async16(Wt + (size_t)n * N_EMBD + kc + csrc * 8, lds + 16384 + j * 1024);
        }
        __syncthreads();

#pragma unroll
        for (int ks = 0; ks < 2; ++ks) {
            const int kq = ks * 4 + quad;       // 16B bf16-chunk index along K
            bf16x8 af[2], bf[6];
#pragma unroll
            for (int rt = 0; rt < 2; ++rt) {
                int m = wm0 + rt * 16 + cl;     // m&15 == cl
                int c0 = kq * 2;                // fp32 chunk index
                f32x4 a0 = *(const f32x4*)(lds + ((m * 16 + (c0 ^ cl)) << 4));
                f32x4 a1 = *(const f32x4*)(lds + ((m * 16 + ((c0 + 1) ^ cl)) << 4));
                bf16x8 t;
                t[0] = (__bf16)a0[0]; t[1] = (__bf16)a0[1];
                t[2] = (__bf16)a0[2]; t[3] = (__bf16)a0[3];
                t[4] = (__bf16)a1[0]; t[5] = (__bf16)a1[1];
                t[6] = (__bf16)a1[2]; t[7] = (__bf16)a1[3];
                af[rt] = t;
            }
#pragma unroll
            for (int ct = 0; ct < 6; ++ct) {
                int n = wn0 + ct * 16 + cl;     // n&7 == l&7
                bf[ct] = *(const bf16x8*)(lds + 16384 + ((n * 8 + (kq ^ (l & 7))) << 4));
            }
#pragma unroll
            for (int rt = 0; rt < 2; ++rt)
#pragma unroll
                for (int ct = 0; ct < 6; ++ct)
                    acc[rt][ct] = __builtin_amdgcn_mfma_f32_16x16x32_bf16(
                        af[rt], bf[ct], acc[rt][ct], 0, 0, 0);
        }
    }

    // Epilogue. C layout: col = cl, row = quad*4 + i (within 16x16 tile).
    const float LNT = 0.07195578430905272f;  // ln(10000)/128
    const int bidx = row0 >> 7;              // batch
    const int srow0 = row0 & 127;            // s-offset of this M-tile in batch
#pragma unroll
    for (int ct = 0; ct < 6; ++ct) {
        int c  = wn0 + ct * 16 + cl;         // 0..383
        int ntc = c >> 7;                    // 0=q 1=k 2=v
        int d  = c & 127;
        if (ntc < 2) {
            unsigned short* dst = (ntc == 0) ? qb : kb;
            float freq = __expf(-(float)(d & ~1) * LNT);
#pragma unroll
            for (int rt = 0; rt < 2; ++rt) {
#pragma unroll
                for (int i = 0; i < 4; ++i) {
                    int grow = row0 + wm0 + rt * 16 + quad * 4 + i;
                    int t = grow & 127;
                    float v = acc[rt][ct][i];
                    float p = __shfl_xor(v, 1);
                    float sn, cs;
                    __sincosf((float)t * freq, &sn, &cs);
                    float r = ((d & 1) == 0) ? (v * cs - p * sn) : (p * sn + v * cs);
                    dst[(size_t)grow * HS + d] = bfbits(r);
                }
            }
        } else {
            // v transposed: vt[b][d][s], 4 consecutive s -> 8 B store
#pragma unroll
            for (int rt = 0; rt < 2; ++rt) {
                int s0 = srow0 + wm0 + rt * 16 + quad * 4;
                us4 u;
                u.x = bfbits(acc[rt][ct][0]);
                u.y = bfbits(acc[rt][ct][1]);
                u.z = bfbits(acc[rt][ct][2]);
                u.w = bfbits(acc[rt][ct][3]);
                *(us4*)(vt + (size_t)bidx * 16384 + d * 128 + s0) = u;
            }
        }
    }
}

// ---------------- Kernel 2: causal attention (MFMA, flash-lite) ----------------
// 2048 blocks x 64 threads (1 wave). Block = (b = bid>>3, rg = bid&7): 16 Q rows
// [rg*16, rg*16+16). Causal skip: score tiles ct <= rg; PV s-chunks < (rg+2)/2.
// Frags from global (L2/L3-hot). P: C-layout -> bf16 LDS -> A-layout.
__global__ __launch_bounds__(64) void attn(
    const unsigned short* __restrict__ qb,
    const unsigned short* __restrict__ kb,
    const unsigned short* __restrict__ vt,
    float* __restrict__ out)
{
    __shared__ char plds[16 * 272];
    const int l = threadIdx.x;
    const int cl = l & 15;
    const int quad = l >> 4;
    const int b  = blockIdx.x >> 3;
    const int rg = blockIdx.x & 7;
    const int nct = rg + 1;
    const int nks = (rg + 2) >> 1;

    const unsigned short* qB = qb + (size_t)b * 16384;
    const unsigned short* kB = kb + (size_t)b * 16384;
    const unsigned short* vB = vt + (size_t)b * 16384;

    // preload all 4 Q A-frags (lets the compiler batch the K-side loads)
    bf16x8 af[4];
#pragma unroll
    for (int ks = 0; ks < 4; ++ks)
        af[ks] = *(const bf16x8*)(qB + (size_t)(rg * 16 + cl) * HS + (ks * 4 + quad) * 8);

    f32x4 s[8];
#pragma unroll
    for (int ct = 0; ct < 8; ++ct) s[ct] = zero4();

#pragma unroll
    for (int ct = 0; ct < 8; ++ct) if (ct < nct) {
        const unsigned short* kr = kB + (size_t)(ct * 16 + cl) * HS;
#pragma unroll
        for (int ks = 0; ks < 4; ++ks) {
            bf16x8 bb = *(const bf16x8*)(kr + (ks * 4 + quad) * 8);
            s[ct] = __builtin_amdgcn_mfma_f32_16x16x32_bf16(af[ks], bb, s[ct], 0, 0, 0);
        }
    }

    // softmax: row t lives in one quad across its 16 cl lanes
    const float scale = 0.08838834764831845f;   // 1/sqrt(128)
#pragma unroll
    for (int i = 0; i < 4; ++i) {
        int t = rg * 16 + quad * 4 + i;
        float mx = -3.0e38f;
#pragma unroll
        for (int ct = 0; ct < 8; ++ct) if (ct < nct) {
            int col = ct * 16 + cl;
            float v = s[ct][i] * scale;
            v = (col <= t) ? v : -INFINITY;
            s[ct][i] = v;
            mx = fmaxf(mx, v);
        }
        mx = fmaxf(mx, __shfl_xor(mx, 1));
        mx = fmaxf(mx, __shfl_xor(mx, 2));
        mx = fmaxf(mx, __shfl_xor(mx, 4));
        mx = fmaxf(mx, __shfl_xor(mx, 8));
        float sum = 0.f;
#pragma unroll
        for (int ct = 0; ct < 8; ++ct) if (ct < nct) {
            float p = __expf(s[ct][i] - mx);
            s[ct][i] = p;
            sum += p;
        }
        sum += __shfl_xor(sum, 1);
        sum += __shfl_xor(sum, 2);
        sum += __shfl_xor(sum, 4);
        sum += __shfl_xor(sum, 8);
        float inv = 1.0f / sum;
        int rl = quad * 4 + i;
#pragma unroll
        for (int ct = 0; ct < 8; ++ct) if (ct < nct) {
            *(unsigned short*)(plds + rl * 272 + (ct * 16 + cl) * 2) =
                bfbits(s[ct][i] * inv);
        }
    }
    // rg even: PV consumes one 16-col tile beyond the last stored -> zero it
    if ((rg & 1) == 0) {
#pragma unroll
        for (int i = 0; i < 4; ++i)
            *(unsigned short*)(plds + (quad * 4 + i) * 272 + (nct * 16 + cl) * 2) = 0;
    }
    // same-wave ds_write -> ds_read: compiler inserts lgkmcnt wait; no barrier.

    bf16x8 ap[4];
#pragma unroll
    for (int ks = 0; ks < 4; ++ks) if (ks < nks)
        ap[ks] = *(const bf16x8*)(plds + cl * 272 + (ks * 4 + quad) * 16);

    f32x4 o[8];
#pragma unroll
    for (int ct = 0; ct < 8; ++ct) o[ct] = zero4();

#pragma unroll
    for (int ct = 0; ct < 8; ++ct) {
        const unsigned short* vr = vB + (size_t)(ct * 16 + cl) * 128;
#pragma unroll
        for (int ks = 0; ks < 4; ++ks) if (ks < nks) {
            bf16x8 bb = *(const bf16x8*)(vr + (ks * 4 + quad) * 8);
            o[ct] = __builtin_amdgcn_mfma_f32_16x16x32_bf16(ap[ks], bb, o[ct], 0, 0, 0);
        }
    }

#pragma unroll
    for (int ct = 0; ct < 8; ++ct)
#pragma unroll
        for (int i = 0; i < 4; ++i) {
            int t = rg * 16 + quad * 4 + i;
            out[(size_t)b * 16384 + (size_t)t * HS + ct * 16 + cl] = o[ct][i];
        }
}

// ---------------- launch ----------------
extern "C" void kernel_launch(void* const* d_in, const int* in_sizes, int n_in,
                              void* d_out, int out_size, void* d_ws, size_t ws_size,
                              hipStream_t stream) {
    const float* x  = (const float*)d_in[0];
    const float* Wq = (const float*)d_in[1];
    const float* Wk = (const float*)d_in[2];
    const float* Wv = (const float*)d_in[3];
    float* out = (float*)d_out;

    unsigned short* qb = (unsigned short*)d_ws;
    unsigned short* kb = qb + (size_t)ROWS * HS;
    unsigned short* vt = kb + (size_t)ROWS * HS;
    unsigned short* Wt = vt + (size_t)ROWS * HS;

    wcast<<<48, 256, 0, stream>>>(Wq, Wk, Wv, Wt);
    qkv_gemm<<<512, 512, 0, stream>>>(x, Wt, qb, kb, vt);
    attn<<<2048, 64, 0, stream>>>(qb, kb, vt, out);
}

// Round 4
// 240.085 us; speedup vs baseline: 3.1346x; 1.0430x over previous
//
#include <hip/hip_runtime.h>
#include <math.h>

typedef __bf16 bf16x8 __attribute__((ext_vector_type(8)));
typedef float  f32x4  __attribute__((ext_vector_type(4)));
typedef unsigned short us4 __attribute__((ext_vector_type(4)));

constexpr int N_EMBD = 1024;
constexpr int T_SEQ  = 128;
constexpr int HS     = 128;
constexpr int BATCH  = 256;
constexpr int ROWS   = BATCH * T_SEQ;   // 32768

__device__ __forceinline__ void async16(const void* g, void* l) {
    __builtin_amdgcn_global_load_lds(
        (const __attribute__((address_space(1))) unsigned int*)g,
        (__attribute__((address_space(3))) unsigned int*)l, 16, 0, 0);
}
__device__ __forceinline__ unsigned short bfbits(float f) {
    return __builtin_bit_cast(unsigned short, (__bf16)f);
}
__device__ __forceinline__ f32x4 zero4() {
    f32x4 z = {0.f, 0.f, 0.f, 0.f};
    return z;
}

// ---------------- Kernel 0: W cast + transpose ----------------
// Wt[nt*128 + n][k] = W_nt[k][n] as bf16.  48 blocks = 3 nt x 16 k-chunks.
__global__ __launch_bounds__(256) void wcast(
    const float* __restrict__ Wq, const float* __restrict__ Wk,
    const float* __restrict__ Wv, unsigned short* __restrict__ Wt)
{
    __shared__ unsigned short tile[64][130];
    const int bid = blockIdx.x;
    const int nt  = bid >> 4;
    const int k0  = (bid & 15) << 6;
    const float* src = (nt == 0) ? Wq : ((nt == 1) ? Wk : Wv);
    const int tid = threadIdx.x;
#pragma unroll
    for (int j = 0; j < 32; ++j) {
        int idx = tid + j * 256;
        int k = idx >> 7, n = idx & 127;
        tile[k][n] = bfbits(src[(size_t)(k0 + k) * HS + n]);
    }
    __syncthreads();
#pragma unroll
    for (int j = 0; j < 32; ++j) {
        int idx = tid + j * 256;
        int n = idx >> 6, kk = idx & 63;
        Wt[(size_t)(nt * 128 + n) * N_EMBD + k0 + kk] = tile[kk][n];
    }
}

// ---------------- Kernel 1: fused QKV GEMM (MFMA) + RoPE ----------------
// 512 blocks x 256 threads (4 waves). Block = 64-row M-tile x all 384 N cols.
// Wave tile 64x96: acc[4][6] 16x16 tiles (read:MFMA ratio 2x better than 32x96).
// A (x) staged global->VGPR->cvt bf16->ds_write_b128 (halves A LDS bytes vs fp32);
// next chunk's A global loads issued AFTER the staging barrier so their HBM
// latency hides under the 48-MFMA compute phase. B (Wt bf16) via global_load_lds.
// Both LDS arrays XOR-swizzled (8 chunks/row): 0 bank conflicts measured so far.
__global__ __launch_bounds__(256, 2) void qkv_gemm(
    const float* __restrict__ x,
    const unsigned short* __restrict__ Wt,
    unsigned short* __restrict__ qb,
    unsigned short* __restrict__ kb,
    unsigned short* __restrict__ vt)
{
    __shared__ char lds[57344];   // A bf16 64x64 = 8192 B | B bf16 384x64 = 49152 B
    const int tid = threadIdx.x;
    const int w  = tid >> 6;
    const int l  = tid & 63;
    const int cl = l & 15;
    const int quad = l >> 4;
    const int row0 = blockIdx.x << 6;
    const int wn0 = w * 96;

    // A staging mapping: thread -> (row ar, 16-float chunk ac); 64B contiguous/thread
    const int ar = tid >> 2;
    const int ac = tid & 3;
    const int aslot0 = (ac * 2) ^ (ar & 7);
    const int aslot1 = (ac * 2 + 1) ^ (ar & 7);
    const float* aptr = x + (size_t)(row0 + ar) * N_EMBD + ac * 16;

    f32x4 acc[4][6];
#pragma unroll
    for (int a = 0; a < 4; ++a)
#pragma unroll
        for (int b = 0; b < 6; ++b) acc[a][b] = zero4();

    // preload first A chunk
    f32x4 ar0 = *(const f32x4*)(aptr);
    f32x4 ar1 = *(const f32x4*)(aptr + 4);
    f32x4 ar2 = *(const f32x4*)(aptr + 8);
    f32x4 ar3 = *(const f32x4*)(aptr + 12);

    for (int kc = 0; kc < N_EMBD; kc += 64) {
        __syncthreads();   // prev compute done: LDS safe to overwrite
        // A: cvt preloaded regs -> bf16, 2x ds_write_b128
        bf16x8 w0, w1;
        w0[0] = (__bf16)ar0[0]; w0[1] = (__bf16)ar0[1];
        w0[2] = (__bf16)ar0[2]; w0[3] = (__bf16)ar0[3];
        w0[4] = (__bf16)ar1[0]; w0[5] = (__bf16)ar1[1];
        w0[6] = (__bf16)ar1[2]; w0[7] = (__bf16)ar1[3];
        w1[0] = (__bf16)ar2[0]; w1[1] = (__bf16)ar2[1];
        w1[2] = (__bf16)ar2[2]; w1[3] = (__bf16)ar2[3];
        w1[4] = (__bf16)ar3[0]; w1[5] = (__bf16)ar3[1];
        w1[6] = (__bf16)ar3[2]; w1[7] = (__bf16)ar3[3];
        *(bf16x8*)(lds + ar * 128 + aslot0 * 16) = w0;
        *(bf16x8*)(lds + ar * 128 + aslot1 * 16) = w1;
        // B: 48 KB via global_load_lds, 12 instr/wave
#pragma unroll
        for (int jj = 0; jj < 12; ++jj) {
            int j = w * 12 + jj;
            int n = j * 8 + (l >> 3);
            int csrc = (l & 7) ^ (l >> 3);
            async16(Wt + (size_t)n * N_EMBD + kc + csrc * 8, lds + 8192 + j * 1024);
        }
        __syncthreads();   // staged data visible (drains A writes + B async)

        // prefetch next A chunk: drains only at NEXT loop-top barrier -> hidden
        if (kc + 64 < N_EMBD) {
            const float* ap2 = aptr + kc + 64;
            ar0 = *(const f32x4*)(ap2);
            ar1 = *(const f32x4*)(ap2 + 4);
            ar2 = *(const f32x4*)(ap2 + 8);
            ar3 = *(const f32x4*)(ap2 + 12);
        }

#pragma unroll
        for (int ks = 0; ks < 2; ++ks) {
            bf16x8 af[4], bf[6];
#pragma unroll
            for (int rt = 0; rt < 4; ++rt) {
                int m = rt * 16 + cl;
                af[rt] = *(const bf16x8*)(lds + m * 128 + (((ks * 4 + quad) ^ (m & 7)) << 4));
            }
#pragma unroll
            for (int ct = 0; ct < 6; ++ct) {
                int n = wn0 + ct * 16 + cl;
                bf[ct] = *(const bf16x8*)(lds + 8192 + n * 128 + (((ks * 4 + quad) ^ (n & 7)) << 4));
            }
#pragma unroll
            for (int rt = 0; rt < 4; ++rt)
#pragma unroll
                for (int ct = 0; ct < 6; ++ct)
                    acc[rt][ct] = __builtin_amdgcn_mfma_f32_16x16x32_bf16(
                        af[rt], bf[ct], acc[rt][ct], 0, 0, 0);
        }
    }

    // Epilogue. C layout: col = cl, row = quad*4 + i (within 16x16 tile).
    const float LNT = 0.07195578430905272f;  // ln(10000)/128
    const int bidx = row0 >> 7;
    const int srow0 = row0 & 127;
#pragma unroll
    for (int ct = 0; ct < 6; ++ct) {
        int c  = wn0 + ct * 16 + cl;         // 0..383
        int ntc = c >> 7;                    // 0=q 1=k 2=v (uniform per 16-col tile)
        int d  = c & 127;
        if (ntc < 2) {
            unsigned short* dst = (ntc == 0) ? qb : kb;
            float freq = __expf(-(float)(d & ~1) * LNT);
#pragma unroll
            for (int rt = 0; rt < 4; ++rt) {
#pragma unroll
                for (int i = 0; i < 4; ++i) {
                    int grow = row0 + rt * 16 + quad * 4 + i;
                    int t = grow & 127;
                    float v = acc[rt][ct][i];
                    float p = __shfl_xor(v, 1);
                    float sn, cs;
                    __sincosf((float)t * freq, &sn, &cs);
                    float r = ((d & 1) == 0) ? (v * cs - p * sn) : (p * sn + v * cs);
                    dst[(size_t)grow * HS + d] = bfbits(r);
                }
            }
        } else {
            // v transposed: vt[b][d][s], 4 consecutive s -> 8 B store
#pragma unroll
            for (int rt = 0; rt < 4; ++rt) {
                int s0 = srow0 + rt * 16 + quad * 4;
                us4 u;
                u.x = bfbits(acc[rt][ct][0]);
                u.y = bfbits(acc[rt][ct][1]);
                u.z = bfbits(acc[rt][ct][2]);
                u.w = bfbits(acc[rt][ct][3]);
                *(us4*)(vt + (size_t)bidx * 16384 + d * 128 + s0) = u;
            }
        }
    }
}

// ---------------- Kernel 2: causal attention (MFMA, flash-lite) ----------------
// 2048 blocks x 64 threads (1 wave). Block = (b, rg): 16 Q rows [rg*16, rg*16+16).
// Templated on RG -> compile-time loop bounds: full unroll, batched global loads.
template<int RG>
__device__ __forceinline__ void attn_body(
    const unsigned short* __restrict__ qB,
    const unsigned short* __restrict__ kB,
    const unsigned short* __restrict__ vB,
    float* __restrict__ outB, char* plds, int l)
{
    constexpr int NCT = RG + 1;
    constexpr int NKS = (RG + 2) >> 1;
    const int cl = l & 15;
    const int quad = l >> 4;

    bf16x8 af[4];
#pragma unroll
    for (int ks = 0; ks < 4; ++ks)
        af[ks] = *(const bf16x8*)(qB + (size_t)(RG * 16 + cl) * HS + (ks * 4 + quad) * 8);

    f32x4 s[NCT];
#pragma unroll
    for (int ct = 0; ct < NCT; ++ct) s[ct] = zero4();

#pragma unroll
    for (int ct = 0; ct < NCT; ++ct) {
        const unsigned short* kr = kB + (size_t)(ct * 16 + cl) * HS;
#pragma unroll
        for (int ks = 0; ks < 4; ++ks) {
            bf16x8 bb = *(const bf16x8*)(kr + (ks * 4 + quad) * 8);
            s[ct] = __builtin_amdgcn_mfma_f32_16x16x32_bf16(af[ks], bb, s[ct], 0, 0, 0);
        }
    }

    const float scale = 0.08838834764831845f;   // 1/sqrt(128)
#pragma unroll
    for (int i = 0; i < 4; ++i) {
        int t = RG * 16 + quad * 4 + i;
        float mx = -3.0e38f;
#pragma unroll
        for (int ct = 0; ct < NCT; ++ct) {
            int col = ct * 16 + cl;
            float v = s[ct][i] * scale;
            v = (col <= t) ? v : -INFINITY;
            s[ct][i] = v;
            mx = fmaxf(mx, v);
        }
        mx = fmaxf(mx, __shfl_xor(mx, 1));
        mx = fmaxf(mx, __shfl_xor(mx, 2));
        mx = fmaxf(mx, __shfl_xor(mx, 4));
        mx = fmaxf(mx, __shfl_xor(mx, 8));
        float sum = 0.f;
#pragma unroll
        for (int ct = 0; ct < NCT; ++ct) {
            float p = __expf(s[ct][i] - mx);
            s[ct][i] = p;
            sum += p;
        }
        sum += __shfl_xor(sum, 1);
        sum += __shfl_xor(sum, 2);
        sum += __shfl_xor(sum, 4);
        sum += __shfl_xor(sum, 8);
        float inv = 1.0f / sum;
        int rl = quad * 4 + i;
#pragma unroll
        for (int ct = 0; ct < NCT; ++ct) {
            *(unsigned short*)(plds + rl * 272 + (ct * 16 + cl) * 2) =
                bfbits(s[ct][i] * inv);
        }
        if ((RG & 1) == 0) {   // PV consumes one 16-col tile past the stored range
            *(unsigned short*)(plds + rl * 272 + (NCT * 16 + cl) * 2) = 0;
        }
    }
    // same-wave ds_write -> ds_read: compiler inserts lgkmcnt wait; no barrier.

    bf16x8 ap[NKS];
#pragma unroll
    for (int ks = 0; ks < NKS; ++ks)
        ap[ks] = *(const bf16x8*)(plds + cl * 272 + (ks * 4 + quad) * 16);

    f32x4 o[8];
#pragma unroll
    for (int ct = 0; ct < 8; ++ct) o[ct] = zero4();

#pragma unroll
    for (int ct = 0; ct < 8; ++ct) {
        const unsigned short* vr = vB + (size_t)(ct * 16 + cl) * 128;
#pragma unroll
        for (int ks = 0; ks < NKS; ++ks) {
            bf16x8 bb = *(const bf16x8*)(vr + (ks * 4 + quad) * 8);
            o[ct] = __builtin_amdgcn_mfma_f32_16x16x32_bf16(ap[ks], bb, o[ct], 0, 0, 0);
        }
    }

#pragma unroll
    for (int ct = 0; ct < 8; ++ct)
#pragma unroll
        for (int i = 0; i < 4; ++i) {
            int t = RG * 16 + quad * 4 + i;
            outB[(size_t)t * HS + ct * 16 + cl] = o[ct][i];
        }
}

__global__ __launch_bounds__(64) void attn(
    const unsigned short* __restrict__ qb,
    const unsigned short* __restrict__ kb,
    const unsigned short* __restrict__ vt,
    float* __restrict__ out)
{
    __shared__ char plds[16 * 272];
    const int l = threadIdx.x;
    const int b  = blockIdx.x >> 3;
    const int rg = blockIdx.x & 7;

    const unsigned short* qB = qb + (size_t)b * 16384;
    const unsigned short* kB = kb + (size_t)b * 16384;
    const unsigned short* vB = vt + (size_t)b * 16384;
    float* outB = out + (size_t)b * 16384;

    switch (rg) {
        case 0: attn_body<0>(qB, kB, vB, outB, plds, l); break;
        case 1: attn_body<1>(qB, kB, vB, outB, plds, l); break;
        case 2: attn_body<2>(qB, kB, vB, outB, plds, l); break;
        case 3: attn_body<3>(qB, kB, vB, outB, plds, l); break;
        case 4: attn_body<4>(qB, kB, vB, outB, plds, l); break;
        case 5: attn_body<5>(qB, kB, vB, outB, plds, l); break;
        case 6: attn_body<6>(qB, kB, vB, outB, plds, l); break;
        default: attn_body<7>(qB, kB, vB, outB, plds, l); break;
    }
}

// ---------------- launch ----------------
extern "C" void kernel_launch(void* const* d_in, const int* in_sizes, int n_in,
                              void* d_out, int out_size, void* d_ws, size_t ws_size,
                              hipStream_t stream) {
    const float* x  = (const float*)d_in[0];
    const float* Wq = (const float*)d_in[1];
    const float* Wk = (const float*)d_in[2];
    const float* Wv = (const float*)d_in[3];
    float* out = (float*)d_out;

    unsigned short* qb = (unsigned short*)d_ws;
    unsigned short* kb = qb + (size_t)ROWS * HS;
    unsigned short* vt = kb + (size_t)ROWS * HS;
    unsigned short* Wt = vt + (size_t)ROWS * HS;

    wcast<<<48, 256, 0, stream>>>(Wq, Wk, Wv, Wt);
    qkv_gemm<<<512, 256, 0, stream>>>(x, Wt, qb, kb, vt);
    attn<<<2048, 64, 0, stream>>>(qb, kb, vt, out);
}

// Round 5
// 226.444 us; speedup vs baseline: 3.3234x; 1.0602x over previous
//
#include <hip/hip_runtime.h>
#include <math.h>

typedef __bf16 bf16x8 __attribute__((ext_vector_type(8)));
typedef float  f32x4  __attribute__((ext_vector_type(4)));
typedef unsigned short us4 __attribute__((ext_vector_type(4)));

constexpr int N_EMBD = 1024;
constexpr int T_SEQ  = 128;
constexpr int HS     = 128;
constexpr int BATCH  = 256;
constexpr int ROWS   = BATCH * T_SEQ;   // 32768

__device__ __forceinline__ void async16(const void* g, void* l) {
    __builtin_amdgcn_global_load_lds(
        (const __attribute__((address_space(1))) unsigned int*)g,
        (__attribute__((address_space(3))) unsigned int*)l, 16, 0, 0);
}
__device__ __forceinline__ unsigned short bfbits(float f) {
    return __builtin_bit_cast(unsigned short, (__bf16)f);
}
__device__ __forceinline__ f32x4 zero4() {
    f32x4 z = {0.f, 0.f, 0.f, 0.f};
    return z;
}

// ---------------- Kernel 0: W cast + transpose ----------------
// Wt[nt*128 + n][k] = W_nt[k][n] as bf16.  48 blocks = 3 nt x 16 k-chunks.
__global__ __launch_bounds__(256) void wcast(
    const float* __restrict__ Wq, const float* __restrict__ Wk,
    const float* __restrict__ Wv, unsigned short* __restrict__ Wt)
{
    __shared__ unsigned short tile[64][130];
    const int bid = blockIdx.x;
    const int nt  = bid >> 4;
    const int k0  = (bid & 15) << 6;
    const float* src = (nt == 0) ? Wq : ((nt == 1) ? Wk : Wv);
    const int tid = threadIdx.x;
#pragma unroll
    for (int j = 0; j < 32; ++j) {
        int idx = tid + j * 256;
        int k = idx >> 7, n = idx & 127;
        tile[k][n] = bfbits(src[(size_t)(k0 + k) * HS + n]);
    }
    __syncthreads();
#pragma unroll
    for (int j = 0; j < 32; ++j) {
        int idx = tid + j * 256;
        int n = idx >> 6, kk = idx & 63;
        Wt[(size_t)(nt * 128 + n) * N_EMBD + k0 + kk] = tile[kk][n];
    }
}

// ---------------- Kernel 1: fully fused head, one block per batch ----------------
// 256 blocks x 512 threads (8 waves), 1 block/CU. LDS (136 KB):
//   QS/KS: q,k bf16 [t][d], 128 rows x 272 B (pad +16 B -> 2-way conflicts max)
//   VS: v bf16 [d][s], 128 x 272 B
//   STG_A: x chunk staging, 128 rows x 80 B (bf16 32 cols + 16 B pad)
//   STG_B: Wt chunk staging, 384 rows x 64 B, XOR-swizzled (chunk ^= (n>>2)&3)
//   P (phase 2) reuses STG_A+STG_B exactly: 8 waves x 16 rows x 272 B.
// Phase 1: QKV GEMM, BK=32. x global->regs (prefetch 1 chunk ahead; 16 KB/CU in
// flight >= BW*latency ~9 KB so the HBM stream stays saturated) ->cvt->LDS.
// Wt via global_load_lds (L2-resident). RoPE fused in epilogue -> q/k/v to LDS.
// Phase 2: per-wave causal attention on 16 Q-rows, all operands from LDS.
__global__ __launch_bounds__(512, 2) void head_fused(
    const float* __restrict__ x,
    const unsigned short* __restrict__ Wt,
    float* __restrict__ out)
{
    __shared__ char lds[139264];
    constexpr int QS = 0;
    constexpr int KS = 34816;
    constexpr int VS = 69632;
    constexpr int STG_A = 104448;
    constexpr int STG_B = 114688;

    const int tid  = threadIdx.x;
    const int w    = tid >> 6;
    const int l    = tid & 63;
    const int cl   = l & 15;
    const int quad = l >> 4;
    const int b    = blockIdx.x;
    const int row0 = b << 7;
    const int wm   = (w & 1) << 6;     // 0 or 64
    const int wn   = (w >> 1) * 96;    // 0,96,192,288

    // ---- phase 1: QKV GEMM ----
    // A staging map: 4 threads/row, 8 floats each
    const int arow = tid >> 2;
    const int acol = (tid & 3) << 3;
    const float* aptr = x + (size_t)(row0 + arow) * N_EMBD + acol;
    const int bsrc = (l & 3) ^ quad;   // B source chunk (XOR swizzle)

    f32x4 acc[4][6];
#pragma unroll
    for (int a = 0; a < 4; ++a)
#pragma unroll
        for (int c = 0; c < 6; ++c) acc[a][c] = zero4();

    f32x4 a0 = *(const f32x4*)(aptr);
    f32x4 a1 = *(const f32x4*)(aptr + 4);

    for (int kc = 0; kc < N_EMBD; kc += 32) {
        __syncthreads();   // prev chunk's frag reads done
        // stage A: cvt 8 floats -> bf16x8, one ds_write_b128
        bf16x8 aw;
        aw[0] = (__bf16)a0[0]; aw[1] = (__bf16)a0[1];
        aw[2] = (__bf16)a0[2]; aw[3] = (__bf16)a0[3];
        aw[4] = (__bf16)a1[0]; aw[5] = (__bf16)a1[1];
        aw[6] = (__bf16)a1[2]; aw[7] = (__bf16)a1[3];
        *(bf16x8*)(lds + STG_A + arow * 80 + (tid & 3) * 16) = aw;
        // stage B: 384 rows x 64 B, 3 async16/thread, lane-contiguous dst
#pragma unroll
        for (int jj = 0; jj < 3; ++jj) {
            int j = w * 3 + jj;
            int n = j * 16 + (l >> 2);
            async16(Wt + (size_t)n * N_EMBD + kc + bsrc * 8,
                    lds + STG_B + j * 1024 + 0);
        }
        __syncthreads();   // staged data visible
        // prefetch next A chunk (drains during this chunk's compute)
        if (kc + 32 < N_EMBD) {
            a0 = *(const f32x4*)(aptr + kc + 32);
            a1 = *(const f32x4*)(aptr + kc + 36);
        }
        // frags + 24 MFMA
        bf16x8 af[4], bf[6];
#pragma unroll
        for (int rt = 0; rt < 4; ++rt) {
            int m = wm + rt * 16 + cl;
            af[rt] = *(const bf16x8*)(lds + STG_A + m * 80 + quad * 16);
        }
#pragma unroll
        for (int ct = 0; ct < 6; ++ct) {
            int n = wn + ct * 16 + cl;
            bf[ct] = *(const bf16x8*)(lds + STG_B + n * 64 + ((quad ^ ((n >> 2) & 3)) << 4));
        }
#pragma unroll
        for (int rt = 0; rt < 4; ++rt)
#pragma unroll
            for (int ct = 0; ct < 6; ++ct)
                acc[rt][ct] = __builtin_amdgcn_mfma_f32_16x16x32_bf16(
                    af[rt], bf[ct], acc[rt][ct], 0, 0, 0);
    }

    // ---- epilogue: RoPE + q/k/v -> LDS ----
    const float LNT = 0.07195578430905272f;   // ln(10000)/128
#pragma unroll
    for (int ct = 0; ct < 6; ++ct) {
        int c0  = wn + ct * 16;
        int ntc = c0 >> 7;                    // 0=q 1=k 2=v, uniform per tile
        int d   = (c0 & 127) + cl;
        if (ntc < 2) {
            int qk = (ntc == 0) ? QS : KS;
            float freq = __expf(-(float)(d & ~1) * LNT);
#pragma unroll
            for (int rt = 0; rt < 4; ++rt) {
#pragma unroll
                for (int i = 0; i < 4; ++i) {
                    int t = wm + rt * 16 + quad * 4 + i;   // position in batch
                    float v = acc[rt][ct][i];
                    float p = __shfl_xor(v, 1);
                    float sn, cs;
                    __sincosf((float)t * freq, &sn, &cs);
                    float r = ((d & 1) == 0) ? (v * cs - p * sn) : (p * sn + v * cs);
                    *(unsigned short*)(lds + qk + t * 272 + d * 2) = bfbits(r);
                }
            }
        } else {
            // v: LDS [d][s], 4 consecutive s -> one 8 B write
#pragma unroll
            for (int rt = 0; rt < 4; ++rt) {
                int s0 = wm + rt * 16 + quad * 4;
                us4 u;
                u.x = bfbits(acc[rt][ct][0]);
                u.y = bfbits(acc[rt][ct][1]);
                u.z = bfbits(acc[rt][ct][2]);
                u.w = bfbits(acc[rt][ct][3]);
                *(us4*)(lds + VS + d * 272 + s0 * 2) = u;
            }
        }
    }
    __syncthreads();   // q/k/v visible to all waves

    // ---- phase 2: causal attention, wave w owns Q rows [w*16, w*16+16) ----
    const int nct = w + 1;
    const int nks = (w + 2) >> 1;
    char* pl = lds + STG_A + w * 4352;   // 16 rows x 272 B per wave

    bf16x8 qf[4];
#pragma unroll
    for (int ks = 0; ks < 4; ++ks)
        qf[ks] = *(const bf16x8*)(lds + QS + (w * 16 + cl) * 272 + (ks * 4 + quad) * 16);

    f32x4 s[8];
#pragma unroll
    for (int ct = 0; ct < 8; ++ct) s[ct] = zero4();

#pragma unroll
    for (int ct = 0; ct < 8; ++ct) if (ct < nct) {
        const char* kr = lds + KS + (ct * 16 + cl) * 272;
#pragma unroll
        for (int ks = 0; ks < 4; ++ks) {
            bf16x8 bb = *(const bf16x8*)(kr + (ks * 4 + quad) * 16);
            s[ct] = __builtin_amdgcn_mfma_f32_16x16x32_bf16(qf[ks], bb, s[ct], 0, 0, 0);
        }
    }

    const float scale = 0.08838834764831845f;   // 1/sqrt(128)
#pragma unroll
    for (int i = 0; i < 4; ++i) {
        int t = w * 16 + quad * 4 + i;
        float mx = -3.0e38f;
#pragma unroll
        for (int ct = 0; ct < 8; ++ct) if (ct < nct) {
            int col = ct * 16 + cl;
            float v = s[ct][i] * scale;
            v = (col <= t) ? v : -INFINITY;
            s[ct][i] = v;
            mx = fmaxf(mx, v);
        }
        mx = fmaxf(mx, __shfl_xor(mx, 1));
        mx = fmaxf(mx, __shfl_xor(mx, 2));
        mx = fmaxf(mx, __shfl_xor(mx, 4));
        mx = fmaxf(mx, __shfl_xor(mx, 8));
        float sum = 0.f;
#pragma unroll
        for (int ct = 0; ct < 8; ++ct) if (ct < nct) {
            float p = __expf(s[ct][i] - mx);
            s[ct][i] = p;
            sum += p;
        }
        sum += __shfl_xor(sum, 1);
        sum += __shfl_xor(sum, 2);
        sum += __shfl_xor(sum, 4);
        sum += __shfl_xor(sum, 8);
        float inv = 1.0f / sum;
        int rl = quad * 4 + i;
#pragma unroll
        for (int ct = 0; ct < 8; ++ct) if (ct < nct) {
            *(unsigned short*)(pl + rl * 272 + (ct * 16 + cl) * 2) =
                bfbits(s[ct][i] * inv);
        }
        if ((w & 1) == 0) {   // PV consumes one 16-col tile past the stored range
            *(unsigned short*)(pl + rl * 272 + (nct * 16 + cl) * 2) = 0;
        }
    }
    // same-wave ds_write -> ds_read: compiler inserts lgkmcnt wait; no barrier.

    bf16x8 ap[4];
#pragma unroll
    for (int ks = 0; ks < 4; ++ks) if (ks < nks)
        ap[ks] = *(const bf16x8*)(pl + cl * 272 + (ks * 4 + quad) * 16);

    f32x4 o[8];
#pragma unroll
    for (int ct = 0; ct < 8; ++ct) o[ct] = zero4();

#pragma unroll
    for (int ct = 0; ct < 8; ++ct) {
        const char* vr = lds + VS + (ct * 16 + cl) * 272;
#pragma unroll
        for (int ks = 0; ks < 4; ++ks) if (ks < nks) {
            bf16x8 bb = *(const bf16x8*)(vr + (ks * 4 + quad) * 16);
            o[ct] = __builtin_amdgcn_mfma_f32_16x16x32_bf16(ap[ks], bb, o[ct], 0, 0, 0);
        }
    }

#pragma unroll
    for (int ct = 0; ct < 8; ++ct)
#pragma unroll
        for (int i = 0; i < 4; ++i) {
            int t = w * 16 + quad * 4 + i;
            out[(size_t)b * 16384 + (size_t)t * HS + ct * 16 + cl] = o[ct][i];
        }
}

// ---------------- launch ----------------
extern "C" void kernel_launch(void* const* d_in, const int* in_sizes, int n_in,
                              void* d_out, int out_size, void* d_ws, size_t ws_size,
                              hipStream_t stream) {
    const float* x  = (const float*)d_in[0];
    const float* Wq = (const float*)d_in[1];
    const float* Wk = (const float*)d_in[2];
    const float* Wv = (const float*)d_in[3];
    float* out = (float*)d_out;

    unsigned short* Wt = (unsigned short*)d_ws;   // 384 x 1024 bf16 = 768 KB

    wcast<<<48, 256, 0, stream>>>(Wq, Wk, Wv, Wt);
    head_fused<<<BATCH, 512, 0, stream>>>(x, Wt, out);
}